// Round 10
// baseline (156.686 us; speedup 1.0000x reference)
//
#include <hip/hip_runtime.h>
#include <hip/hip_bf16.h>

// Problem constants (match reference)
#define N_NODES   20000
#define DX        16
#define DS        64
#define NLAB      10
#define NSMAT     64
#define E_HALF    160000
#define E_TOT     320000
#define N_LABELED 2000
#define N_HIDDEN  6

#define PAIRS 32                  // pairs per tile (64 edges)
#define NT    (E_HALF / PAIRS)    // 5000 tiles = grid size

typedef short bf16x8 __attribute__((ext_vector_type(8)));
typedef float f32x4  __attribute__((ext_vector_type(4)));
#define MFMA16(a, b, c) __builtin_amdgcn_mfma_f32_16x16x32_bf16((a), (b), (c), 0, 0, 0)

// ---- LDS layout (bytes), total 32768 -> 5 blocks/CU (5*32768 = 160KiB exactly) ----
// Lifetimes: A0 [stage..L0] then MA [final..end] (same 16KB region);
// H0/H1 ping-pong [L0..final-read]; MT [final-write..end] OVERLAYS H0+H1
// (safe: final reads H frags to regs, then barrier, then writes MA/MT).
#define LDS_A0    0        // 16KB  [64 rows][256B] swizzled A0 -> reused as MA
#define LDS_H0    16384    // 8KB   [64 rows][128B] swizzled bf16
#define LDS_H1    24576    // 8KB
#define LDS_MT    16384    // 16KB  b-edge M col-major, overlays H0+H1
#define LDS_TOTAL 32768

// Row swizzle: keeps row bit 3 (old (row&7)<<4 made rows r and r+8 collide)
#define SWZ(row)  ((((row) & 7) << 4) ^ (((row) & 8) << 2))
// MT column spread: folds lane-col bits into bank bits 2,3 (byte bits 4,5)
#define CSP(c)    (((c) & 12) << 2)

// ---- d_ws layout (bytes) ----
#define WS_W0     0        // 16KB frag-packed W0
#define WS_WH     16384    // 48KB frag-packed Wh
#define WS_WOUT   65536    // 32KB frag-packed Wout
#define WS_FLOATS 98304    // newx | deg | accum[4] | orth_part[256]

// ---------------- small helpers ----------------
__device__ __forceinline__ unsigned short f2bf(float f) {   // used only in k_prep
    unsigned int u = __float_as_uint(f);
    unsigned int r = (u + 0x7fffu + ((u >> 16) & 1u)) >> 16;  // RNE
    return (unsigned short)r;
}
// HW packed converter (RNE); no builtin on gfx950 -> inline asm
__device__ __forceinline__ unsigned int cvtpk(float lo, float hi) {
    unsigned int r;
    asm("v_cvt_pk_bf16_f32 %0, %1, %2" : "=v"(r) : "v"(lo), "v"(hi));
    return r;
}
__device__ __forceinline__ float bflo(unsigned int u) { return __uint_as_float(u << 16); }
__device__ __forceinline__ float bfhi(unsigned int u) { return __uint_as_float(u & 0xffff0000u); }

// ---------------- K0: pack weights into MFMA B-fragment order ----------------
// B-frag for 16x16x32: lane l holds B[k = 8*(l>>4)+j][n0 + (l&15)], j=0..7.
__global__ void k_prep(const float* __restrict__ Win, const float* __restrict__ Wh,
                       const float* __restrict__ Wout, unsigned short* __restrict__ wsw) {
    const int idx = blockIdx.x * 256 + threadIdx.x;   // 0..49151
    if (idx >= 49152) return;
    float val; int base, KK, k, n;
    if (idx < 8192) {                 // W0: [128][64]
        k = idx >> 6; n = idx & 63; val = Win[idx]; base = WS_W0 / 2; KK = 4;
    } else if (idx < 32768) {         // Wh: [6][64][64]
        const int r = idx - 8192; const int l = r >> 12; const int rr = r & 4095;
        k = rr >> 6; n = rr & 63; val = Wh[r]; base = (WS_WH + l * 8192) / 2; KK = 2;
    } else {                          // Wout: [64][256]
        const int r = idx - 32768; k = r >> 8; n = r & 255;
        val = Wout[r]; base = WS_WOUT / 2; KK = 2;
    }
    const int ntile = n >> 4, kk = k >> 5, hi = (k >> 3) & 3, j = k & 7;
    const int lane = hi * 16 + (n & 15);
    wsw[base + (((ntile * KK + kk) * 64 + lane) * 8 + j)] = f2bf(val);
}

// ---------------- zero-init ----------------
__global__ void k_zero(float* __restrict__ p, int n) {
    int i = blockIdx.x * blockDim.x + threadIdx.x;
    const int stride = gridDim.x * blockDim.x;
    for (; i < n; i += stride) p[i] = 0.0f;
}

// ---------------- K1: one tile per block; weights streamed from L2 ----------------
__global__ __launch_bounds__(256, 5) void k_main(
    const float* __restrict__ xembed, const float* __restrict__ sembed,
    const float* __restrict__ edge_w,
    const float* __restrict__ bin, const float* __restrict__ bh,
    const float* __restrict__ bout,
    const int* __restrict__ src, const int* __restrict__ tgt,
    const unsigned short* __restrict__ wsw,
    float* __restrict__ newx, float* __restrict__ deg,
    float* __restrict__ orth_part)
{
    extern __shared__ char lds[];
    const int tid    = threadIdx.x;
    const int lane   = tid & 63;
    const int wv     = tid >> 6;       // waves 0,1 own a-edges; 2,3 b-edges
    const int lane15 = lane & 15;
    const int hi     = lane >> 4;
    const int p0     = blockIdx.x * PAIRS;

    // ---- stage A0 (64x128 bf16, swizzled); X quarter stays in regs ----
    float4 sx;
    {
        const int si = tid >> 3, sc = tid & 7;
        const bool sT = (sc >= 4); const int scc = sc & 3;
        const int p = p0 + si;
        const int nodeA = sT ? tgt[p] : src[p];
        const float4* nrow = (const float4*)(sembed + (size_t)nodeA * DS + scc * 16);
        const float4 v0 = nrow[0], v1 = nrow[1], v2 = nrow[2], v3 = nrow[3];
        const int colA = (sT ? 128 : 0) + scc * 32;
        const int colB = (sT ? 0 : 128) + scc * 32;
        const int sXor = SWZ(si);     // rows si and 32+si share (row&15) -> same mask
        uint2 pk;
        pk.x = cvtpk(v0.x, v0.y); pk.y = cvtpk(v0.z, v0.w);
        *(uint2*)(lds + LDS_A0 + si * 256 + ((colA + 0) ^ sXor)) = pk;
        *(uint2*)(lds + LDS_A0 + (32 + si) * 256 + ((colB + 0) ^ sXor)) = pk;
        pk.x = cvtpk(v1.x, v1.y); pk.y = cvtpk(v1.z, v1.w);
        *(uint2*)(lds + LDS_A0 + si * 256 + ((colA + 8) ^ sXor)) = pk;
        *(uint2*)(lds + LDS_A0 + (32 + si) * 256 + ((colB + 8) ^ sXor)) = pk;
        pk.x = cvtpk(v2.x, v2.y); pk.y = cvtpk(v2.z, v2.w);
        *(uint2*)(lds + LDS_A0 + si * 256 + ((colA + 16) ^ sXor)) = pk;
        *(uint2*)(lds + LDS_A0 + (32 + si) * 256 + ((colB + 16) ^ sXor)) = pk;
        pk.x = cvtpk(v3.x, v3.y); pk.y = cvtpk(v3.z, v3.w);
        *(uint2*)(lds + LDS_A0 + si * 256 + ((colA + 24) ^ sXor)) = pk;
        *(uint2*)(lds + LDS_A0 + (32 + si) * 256 + ((colB + 24) ^ sXor)) = pk;

        const int sed = tid >> 2, sqq = tid & 3;   // X: thread == its epilogue thread
        const int nodeX = (sed < 32) ? src[p0 + sed] : tgt[p0 + sed - 32];
        sx = *(const float4*)(xembed + (size_t)nodeX * DX + sqq * 4);
    }

    // L0 bias (4 regs, statically indexed)
    float bin_r[4];
    #pragma unroll
    for (int n = 0; n < 4; ++n) bin_r[n] = bin[16 * n + lane15];

    const int arow = 16 * wv + lane15;
    const int axor = SWZ(arow);

    __syncthreads();   // staging visible

    // ==== layer 0: A0[64x128] @ W0[128x64] -> H0 ====
    {
        bf16x8 a[4];
        #pragma unroll
        for (int kk = 0; kk < 4; ++kk)
            a[kk] = *(const bf16x8*)(lds + LDS_A0 + arow * 256 + ((kk * 64 + hi * 16) ^ axor));
        const unsigned short* w0g = wsw + WS_W0 / 2;
        #pragma unroll
        for (int n = 0; n < 4; ++n) {
            f32x4 acc = {0.0f, 0.0f, 0.0f, 0.0f};
            #pragma unroll
            for (int kk = 0; kk < 4; ++kk) {
                const bf16x8 b = *(const bf16x8*)(w0g + ((n * 4 + kk) * 64 + lane) * 8);
                acc = MFMA16(a[kk], b, acc);
            }
            #pragma unroll
            for (int r = 0; r < 4; ++r) {
                const int row = 16 * wv + 4 * hi + r;
                *(__hip_bfloat16*)(lds + LDS_H0 + row * 128 +
                    (((16 * n + lane15) * 2) ^ SWZ(row))) =
                    __float2bfloat16(fmaxf(acc[r] + bin_r[n], 0.0f));
            }
        }
    }
    __syncthreads();   // all A0 reads done -> region becomes MA

    // ==== 6 hidden layers, H0/H1 ping-pong; rotating 1-ahead bias prefetch ====
    float bcur[4], bnxt[4];
    {
        const float* bl = bh + lane15;
        bcur[0] = bl[0]; bcur[1] = bl[16]; bcur[2] = bl[32]; bcur[3] = bl[48];
    }
    #pragma unroll
    for (int l = 0; l < N_HIDDEN; ++l) {
        if (l + 1 < N_HIDDEN) {
            const float* bl = bh + (l + 1) * 64 + lane15;
            bnxt[0] = bl[0]; bnxt[1] = bl[16]; bnxt[2] = bl[32]; bnxt[3] = bl[48];
        }
        const int sB = (l & 1) ? LDS_H1 : LDS_H0;
        const int dB = (l & 1) ? LDS_H0 : LDS_H1;
        const unsigned short* whg = wsw + WS_WH / 2 + l * 4096;
        const bf16x8 a0 = *(const bf16x8*)(lds + sB + arow * 128 + ((hi * 16) ^ axor));
        const bf16x8 a1 = *(const bf16x8*)(lds + sB + arow * 128 + ((64 + hi * 16) ^ axor));
        #pragma unroll
        for (int n = 0; n < 4; ++n) {
            f32x4 acc = {0.0f, 0.0f, 0.0f, 0.0f};
            const bf16x8 b0 = *(const bf16x8*)(whg + ((n * 2 + 0) * 64 + lane) * 8);
            const bf16x8 b1 = *(const bf16x8*)(whg + ((n * 2 + 1) * 64 + lane) * 8);
            acc = MFMA16(a0, b0, acc);
            acc = MFMA16(a1, b1, acc);
            #pragma unroll
            for (int r = 0; r < 4; ++r) {
                const int row = 16 * wv + 4 * hi + r;
                *(__hip_bfloat16*)(lds + dB + row * 128 +
                    (((16 * n + lane15) * 2) ^ SWZ(row))) =
                    __float2bfloat16(fmaxf(acc[r] + bcur[n], 0.0f));
            }
        }
        bcur[0] = bnxt[0]; bcur[1] = bnxt[1]; bcur[2] = bnxt[2]; bcur[3] = bnxt[3];
    }

    // ==== final layer: read H frags to regs, barrier (H dead -> MT writable) ====
    const bf16x8 fa0 = *(const bf16x8*)(lds + LDS_H0 + arow * 128 + ((hi * 16) ^ axor));
    const bf16x8 fa1 = *(const bf16x8*)(lds + LDS_H0 + arow * 128 + ((64 + hi * 16) ^ axor));
    __syncthreads();   // all H reads done; MT region (overlays H0/H1) now writable

    {
        float bo[16];
        #pragma unroll
        for (int n = 0; n < 16; ++n) bo[n] = bout[16 * n + lane15];

        const unsigned short* wog = wsw + WS_WOUT / 2;
        if (wv < 2) {
            // a-edges: MA row-major, conflict-free scalar writes under SWZ
            #pragma unroll
            for (int n = 0; n < 16; ++n) {
                const bf16x8 b0 = *(const bf16x8*)(wog + ((n * 2 + 0) * 64 + lane) * 8);
                const bf16x8 b1 = *(const bf16x8*)(wog + ((n * 2 + 1) * 64 + lane) * 8);
                f32x4 acc = {0.0f, 0.0f, 0.0f, 0.0f};
                acc = MFMA16(fa0, b0, acc);
                acc = MFMA16(fa1, b1, acc);
                #pragma unroll
                for (int r = 0; r < 4; ++r) {
                    const int i = 16 * wv + 4 * hi + r;
                    *(__hip_bfloat16*)(lds + LDS_A0 + i * 512 +
                        (((n * 16 + lane15) * 2) ^ SWZ(i))) =
                        __float2bfloat16(acc[r] + bo[n]);
                }
            }
        } else {
            // b-edges: MT col-major; buffer 16 Mrow values per r, write 2x b128
            unsigned int pk0[8], pk1[8], pk2[8], pk3[8];
            float tmp0 = 0.f, tmp1 = 0.f, tmp2 = 0.f, tmp3 = 0.f;
            #pragma unroll
            for (int n = 0; n < 16; ++n) {
                const bf16x8 b0 = *(const bf16x8*)(wog + ((n * 2 + 0) * 64 + lane) * 8);
                const bf16x8 b1 = *(const bf16x8*)(wog + ((n * 2 + 1) * 64 + lane) * 8);
                f32x4 acc = {0.0f, 0.0f, 0.0f, 0.0f};
                acc = MFMA16(fa0, b0, acc);
                acc = MFMA16(fa1, b1, acc);
                const float v0 = acc[0] + bo[n], v1 = acc[1] + bo[n];
                const float v2 = acc[2] + bo[n], v3 = acc[3] + bo[n];
                if (n & 1) {
                    pk0[n >> 1] = cvtpk(tmp0, v0); pk1[n >> 1] = cvtpk(tmp1, v1);
                    pk2[n >> 1] = cvtpk(tmp2, v2); pk3[n >> 1] = cvtpk(tmp3, v3);
                } else {
                    tmp0 = v0; tmp1 = v1; tmp2 = v2; tmp3 = v3;
                }
            }
            const int csp = CSP(lane15);
            #pragma unroll
            for (int r = 0; r < 4; ++r) {
                const int i = 16 * (wv - 2) + 4 * hi + r;
                const int sw = SWZ(i) ^ csp;
                char* base = lds + LDS_MT + i * 512;
                const unsigned int* pkr = (r == 0) ? pk0 : (r == 1) ? pk1 : (r == 2) ? pk2 : pk3;
                *(uint4*)(base + ((lane15 * 32 + 0) ^ sw)) =
                    make_uint4(pkr[0], pkr[1], pkr[2], pkr[3]);
                *(uint4*)(base + ((lane15 * 32 + 16) ^ sw)) =
                    make_uint4(pkr[4], pkr[5], pkr[6], pkr[7]);
            }
        }
    }
    __syncthreads();   // M visible block-wide

    // ==== epilogue: messages + scatter (4 threads/edge); X assembled via shfl ====
    {
        const int e = tid >> 2, q = tid & 3;
        const int i = e & 31;
        const bool isB = (e >= 32);
        float xv[16];
        #pragma unroll
        for (int qq = 0; qq < 4; ++qq) {
            xv[4 * qq + 0] = __shfl(sx.x, qq, 4);
            xv[4 * qq + 1] = __shfl(sx.y, qq, 4);
            xv[4 * qq + 2] = __shfl(sx.z, qq, 4);
            xv[4 * qq + 3] = __shfl(sx.w, qq, 4);
        }
        const int p = p0 + i;
        const float w_e  = isB ? edge_w[p + E_HALF] : edge_w[p];
        const int target = isB ? src[p] : tgt[p];
        const int ixor = SWZ(i);
        if (!isB) {
            #pragma unroll
            for (int jj = 0; jj < 4; ++jj) {
                const int row = 4 * q + jj;
                const uint4 m0 = *(const uint4*)(lds + LDS_A0 + i * 512 + ((row * 32) ^ ixor));
                const uint4 m1 = *(const uint4*)(lds + LDS_A0 + i * 512 + ((row * 32 + 16) ^ ixor));
                float m = bflo(m0.x) * xv[0];
                m = fmaf(bfhi(m0.x), xv[1], m);  m = fmaf(bflo(m0.y), xv[2], m);
                m = fmaf(bfhi(m0.y), xv[3], m);  m = fmaf(bflo(m0.z), xv[4], m);
                m = fmaf(bfhi(m0.z), xv[5], m);  m = fmaf(bflo(m0.w), xv[6], m);
                m = fmaf(bfhi(m0.w), xv[7], m);  m = fmaf(bflo(m1.x), xv[8], m);
                m = fmaf(bfhi(m1.x), xv[9], m);  m = fmaf(bflo(m1.y), xv[10], m);
                m = fmaf(bfhi(m1.y), xv[11], m); m = fmaf(bflo(m1.z), xv[12], m);
                m = fmaf(bfhi(m1.z), xv[13], m); m = fmaf(bflo(m1.w), xv[14], m);
                m = fmaf(bfhi(m1.w), xv[15], m);
                atomicAdd(&newx[(size_t)target * DX + row], w_e * m);
            }
        } else {
            float macc[4] = {0.f, 0.f, 0.f, 0.f};
            #pragma unroll
            for (int c = 0; c < 16; ++c) {
                const uint2 v = *(const uint2*)(lds + LDS_MT + i * 512 +
                                                ((c * 32 + q * 8) ^ ixor ^ CSP(c)));
                const float xc = xv[c];
                macc[0] = fmaf(bflo(v.x), xc, macc[0]);
                macc[1] = fmaf(bfhi(v.x), xc, macc[1]);
                macc[2] = fmaf(bflo(v.y), xc, macc[2]);
                macc[3] = fmaf(bfhi(v.y), xc, macc[3]);
            }
            #pragma unroll
            for (int jj = 0; jj < 4; ++jj)
                atomicAdd(&newx[(size_t)target * DX + 4 * q + jj], w_e * macc[jj]);
        }
        if (q == 0) atomicAdd(&deg[target], w_e);
    }

    // ==== epilogue: orth (one mfma per pair; K=16 of 32 used) ====
    float wsum = 0.0f;
    {
        const bf16x8 zf = {0, 0, 0, 0, 0, 0, 0, 0};
        #pragma unroll
        for (int pp = 0; pp < 8; ++pp) {
            const int pi = 8 * wv + pp;
            const int pxor = SWZ(pi);
            const int offA = (lane15 * 32 + (hi & 1) * 16) ^ pxor;
            const int offB = (lane15 * 32 + (hi & 1) * 16) ^ pxor ^ CSP(lane15);
            bf16x8 af  = *(const bf16x8*)(lds + LDS_A0 + pi * 512 + offA);
            bf16x8 bfr = *(const bf16x8*)(lds + LDS_MT + pi * 512 + offB);
            if (hi >= 2) { af = zf; bfr = zf; }
            f32x4 pr = {0.f, 0.f, 0.f, 0.f};
            pr = MFMA16(af, bfr, pr);
            float ss = 0.0f;
            #pragma unroll
            for (int r = 0; r < 4; ++r) {
                const float d = pr[r] - ((4 * hi + r == lane15) ? 1.0f : 0.0f);
                ss = fmaf(d, d, ss);
            }
            #pragma unroll
            for (int o = 32; o > 0; o >>= 1) ss += __shfl_xor(ss, o, 64);
            wsum += sqrtf(ss);
        }
    }
    // block-reduce orth into 256-slot partial array (scratch in dead MA region)
    __syncthreads();
    if (lane == 0) ((float*)(lds + LDS_A0))[wv] = wsum;
    __syncthreads();
    if (tid == 0) {
        const float* pw = (const float*)(lds + LDS_A0);
        atomicAdd(&orth_part[blockIdx.x & 255], pw[0] + pw[1] + pw[2] + pw[3]);
    }
}

// ---------------- block reduction helper (256-thread blocks) ----------------
__device__ __forceinline__ float block_reduce_256(float v) {
    __shared__ float part[4];
    #pragma unroll
    for (int off = 32; off > 0; off >>= 1) v += __shfl_xor(v, off, 64);
    const int lane = threadIdx.x & 63, wid = threadIdx.x >> 6;
    if (lane == 0) part[wid] = v;
    __syncthreads();
    float s = 0.0f;
    if (threadIdx.x == 0) {
        #pragma unroll
        for (int i = 0; i < 4; ++i) s += part[i];
    }
    return s;
}

// K2: degree-normalize (xmaped in place) + smap MSE
__global__ __launch_bounds__(256) void k_smap(
    const float* __restrict__ xembed, float* __restrict__ nx,
    const float* __restrict__ deg, float* __restrict__ accum)
{
    const int n = blockIdx.x * 256 + threadIdx.x;
    float ss = 0.0f;
    if (n < N_NODES) {
        const float d = deg[n];
        const float inv = 1.0f / fmaxf(d, 1e-20f);
        #pragma unroll
        for (int c = 0; c < DX; ++c) {
            const float v  = nx[(size_t)n * DX + c];
            const float xm = (d > 0.0f) ? v * inv : v;
            nx[(size_t)n * DX + c] = xm;
            const float df = xm - xembed[(size_t)n * DX + c];
            ss = fmaf(df, df, ss);
        }
    }
    ss = block_reduce_256(ss);
    if (threadIdx.x == 0) atomicAdd(&accum[1], ss);
}

// K3: KL on labeled nodes
__global__ __launch_bounds__(256) void k_lbpr(
    const float* __restrict__ ylprob, const float* __restrict__ xmaped,
    const float* __restrict__ clW, const float* __restrict__ clb,
    const int* __restrict__ idvert, float* __restrict__ accum)
{
    const int v = blockIdx.x * 256 + threadIdx.x;
    float kl = 0.0f;
    if (v < N_LABELED) {
        const int n = idvert[v];
        float z[NLAB];
        #pragma unroll
        for (int c = 0; c < NLAB; ++c) z[c] = clb[c];
        #pragma unroll
        for (int i = 0; i < DX; ++i) {
            const float xi = xmaped[(size_t)n * DX + i];
            #pragma unroll
            for (int c = 0; c < NLAB; ++c) z[c] = fmaf(xi, clW[i * NLAB + c], z[c]);
        }
        float mx = z[0];
        #pragma unroll
        for (int c = 1; c < NLAB; ++c) mx = fmaxf(mx, z[c]);
        float se = 0.0f;
        #pragma unroll
        for (int c = 0; c < NLAB; ++c) se += expf(z[c] - mx);
        const float lse = mx + logf(se);
        #pragma unroll
        for (int c = 0; c < NLAB; ++c) {
            const float yl = ylprob[(size_t)n * NLAB + c];
            kl += expf(yl) * (yl - (z[c] - lse));
        }
    }
    kl = block_reduce_256(kl);
    if (threadIdx.x == 0) atomicAdd(&accum[2], kl);
}

// K4: finalize the 4 outputs (f32); sums orth partials
__global__ __launch_bounds__(256) void k_final(
    const float* __restrict__ accum, const float* __restrict__ orth_part,
    float* __restrict__ out)
{
    float v = orth_part[threadIdx.x];
    v = block_reduce_256(v);
    if (threadIdx.x == 0) {
        out[0] = v * (1.0f / (float)E_HALF);
        out[1] = 0.0f;                                // loss_cons == 0 exactly
        out[2] = accum[1] * (1.0f / (float)N_NODES);  // mean*DX/(N*DX) = sum/N
        out[3] = accum[2] * (1.0f / (float)N_LABELED);
    }
}

extern "C" void kernel_launch(void* const* d_in, const int* in_sizes, int n_in,
                              void* d_out, int out_size, void* d_ws, size_t ws_size,
                              hipStream_t stream) {
    const float* xembed = (const float*)d_in[0];
    const float* sembed = (const float*)d_in[1];
    const float* ylprob = (const float*)d_in[2];
    const float* edge_w = (const float*)d_in[3];
    const float* Win    = (const float*)d_in[4];
    const float* bin    = (const float*)d_in[5];
    const float* Wh     = (const float*)d_in[6];
    const float* bh     = (const float*)d_in[7];
    const float* Wout   = (const float*)d_in[8];
    const float* bout   = (const float*)d_in[9];
    const float* clW    = (const float*)d_in[10];
    const float* clb    = (const float*)d_in[11];
    const int*   src    = (const int*)d_in[12];
    const int*   tgt    = (const int*)d_in[13];
    const int*   idvert = (const int*)d_in[16];
    // rev1/rev2 implied: pairs are (p, p+E_HALF)

    unsigned short* wsw = (unsigned short*)d_ws;
    float* wsF       = (float*)((char*)d_ws + WS_FLOATS);
    float* newx      = wsF;
    float* deg       = wsF + (size_t)N_NODES * DX;
    float* accum     = deg + N_NODES;
    float* orth_part = accum + 4;
    const int nzero = N_NODES * DX + N_NODES + 4 + 256;

    k_prep<<<192, 256, 0, stream>>>(Win, Wh, Wout, wsw);
    k_zero<<<512, 256, 0, stream>>>(wsF, nzero);

    k_main<<<NT, 256, LDS_TOTAL, stream>>>(
        xembed, sembed, edge_w, bin, bh, bout, src, tgt, wsw, newx, deg, orth_part);

    k_smap<<<(N_NODES + 255) / 256, 256, 0, stream>>>(xembed, newx, deg, accum);
    k_lbpr<<<(N_LABELED + 255) / 256, 256, 0, stream>>>(ylprob, newx, clW, clb, idvert, accum);
    k_final<<<1, 256, 0, stream>>>(accum, orth_part, (float*)d_out);
}

// Round 11
// 129.391 us; speedup vs baseline: 1.2110x; 1.2110x over previous
//
#include <hip/hip_runtime.h>
#include <hip/hip_bf16.h>

// Problem constants (match reference)
#define N_NODES   20000
#define DX        16
#define DS        64
#define NLAB      10
#define NSMAT     64
#define E_HALF    160000
#define E_TOT     320000
#define N_LABELED 2000
#define N_HIDDEN  6

#define PAIRS 32                  // pairs per tile (64 edges)
#define NT    (E_HALF / PAIRS)    // 5000 tiles = grid size

typedef short bf16x8 __attribute__((ext_vector_type(8)));
typedef float f32x4  __attribute__((ext_vector_type(4)));
#define MFMA16(a, b, c) __builtin_amdgcn_mfma_f32_16x16x32_bf16((a), (b), (c), 0, 0, 0)

// ---- LDS layout (bytes), total 40960 -> 4 blocks/CU ----
// Lifetimes: A0 [stage..L0-read] then MA [final-write..end] (same region;
// ordered by the post-hidden barrier). H0 lives [L0..final-read].
// H1 ping-pong partner; MT OVERLAYS H1 (H1 dead after layer 5; the
// post-hidden barrier separates).
#define LDS_A0    0        // 16KB  [64 rows][256B] swizzled A0 -> reused as MA
#define LDS_H0    16384    // 8KB   [64 rows][128B] swizzled bf16
#define LDS_H1    24576    // 8KB   (inside MT region)
#define LDS_MT    24576    // 16KB  b-edge M col-major, overlays H1
#define LDS_TOTAL 40960

// Row swizzle incl. bit 3 (rows r / r+8 no longer collide)
#define SWZ(row)  ((((row) & 7) << 4) ^ (((row) & 8) << 2))
// MT column spread: folds col bits 2,3 into byte bits 4,5
#define CSP(c)    (((c) & 12) << 2)

// ---- d_ws layout (bytes) ----
#define WS_W0     0        // 16KB frag-packed W0
#define WS_WH     16384    // 48KB frag-packed Wh
#define WS_WOUT   65536    // 32KB frag-packed Wout
#define WS_FLOATS 98304    // newx | deg | accum[4] | orth_part[256]

// ---------------- small helpers ----------------
__device__ __forceinline__ unsigned short f2bf(float f) {   // used only in k_prep
    unsigned int u = __float_as_uint(f);
    unsigned int r = (u + 0x7fffu + ((u >> 16) & 1u)) >> 16;  // RNE
    return (unsigned short)r;
}
__device__ __forceinline__ unsigned int cvtpk(float lo, float hi) {
    unsigned int r;
    asm("v_cvt_pk_bf16_f32 %0, %1, %2" : "=v"(r) : "v"(lo), "v"(hi));
    return r;
}
__device__ __forceinline__ float bflo(unsigned int u) { return __uint_as_float(u << 16); }
__device__ __forceinline__ float bfhi(unsigned int u) { return __uint_as_float(u & 0xffff0000u); }

// ---------------- K0: pack weights into MFMA B-fragment order ----------------
__global__ void k_prep(const float* __restrict__ Win, const float* __restrict__ Wh,
                       const float* __restrict__ Wout, unsigned short* __restrict__ wsw) {
    const int idx = blockIdx.x * 256 + threadIdx.x;   // 0..49151
    if (idx >= 49152) return;
    float val; int base, KK, k, n;
    if (idx < 8192) {                 // W0: [128][64]
        k = idx >> 6; n = idx & 63; val = Win[idx]; base = WS_W0 / 2; KK = 4;
    } else if (idx < 32768) {         // Wh: [6][64][64]
        const int r = idx - 8192; const int l = r >> 12; const int rr = r & 4095;
        k = rr >> 6; n = rr & 63; val = Wh[r]; base = (WS_WH + l * 8192) / 2; KK = 2;
    } else {                          // Wout: [64][256]
        const int r = idx - 32768; k = r >> 8; n = r & 255;
        val = Wout[r]; base = WS_WOUT / 2; KK = 2;
    }
    const int ntile = n >> 4, kk = k >> 5, hi = (k >> 3) & 3, j = k & 7;
    const int lane = hi * 16 + (n & 15);
    wsw[base + (((ntile * KK + kk) * 64 + lane) * 8 + j)] = f2bf(val);
}

// ---------------- zero-init ----------------
__global__ void k_zero(float* __restrict__ p, int n) {
    int i = blockIdx.x * blockDim.x + threadIdx.x;
    const int stride = gridDim.x * blockDim.x;
    for (; i < n; i += stride) p[i] = 0.0f;
}

// ---------------- K1: one tile per block; weights streamed with reg dbuf ----------------
__global__ __launch_bounds__(256, 4) void k_main(
    const float* __restrict__ xembed, const float* __restrict__ sembed,
    const float* __restrict__ edge_w,
    const float* __restrict__ bin, const float* __restrict__ bh,
    const float* __restrict__ bout,
    const int* __restrict__ src, const int* __restrict__ tgt,
    const unsigned short* __restrict__ wsw,
    float* __restrict__ newx, float* __restrict__ deg,
    float* __restrict__ orth_part)
{
    extern __shared__ char lds[];
    const int tid    = threadIdx.x;
    const int lane   = tid & 63;
    const int wv     = tid >> 6;       // waves 0,1 own a-edges; 2,3 b-edges
    const int lane15 = lane & 15;
    const int hi     = lane >> 4;
    const int p0     = blockIdx.x * PAIRS;

    // ---- stage A0 (64x128 bf16, swizzled); X quarter stays in regs ----
    float4 sx;
    {
        const int si = tid >> 3, sc = tid & 7;
        const bool sT = (sc >= 4); const int scc = sc & 3;
        const int p = p0 + si;
        const int nodeA = sT ? tgt[p] : src[p];
        const float4* nrow = (const float4*)(sembed + (size_t)nodeA * DS + scc * 16);
        const float4 v0 = nrow[0], v1 = nrow[1], v2 = nrow[2], v3 = nrow[3];
        const int colA = (sT ? 128 : 0) + scc * 32;
        const int colB = (sT ? 0 : 128) + scc * 32;
        const int sXor = SWZ(si);     // rows si and 32+si share bits 0-3 -> same mask
        uint2 pk;
        pk.x = cvtpk(v0.x, v0.y); pk.y = cvtpk(v0.z, v0.w);
        *(uint2*)(lds + LDS_A0 + si * 256 + ((colA + 0) ^ sXor)) = pk;
        *(uint2*)(lds + LDS_A0 + (32 + si) * 256 + ((colB + 0) ^ sXor)) = pk;
        pk.x = cvtpk(v1.x, v1.y); pk.y = cvtpk(v1.z, v1.w);
        *(uint2*)(lds + LDS_A0 + si * 256 + ((colA + 8) ^ sXor)) = pk;
        *(uint2*)(lds + LDS_A0 + (32 + si) * 256 + ((colB + 8) ^ sXor)) = pk;
        pk.x = cvtpk(v2.x, v2.y); pk.y = cvtpk(v2.z, v2.w);
        *(uint2*)(lds + LDS_A0 + si * 256 + ((colA + 16) ^ sXor)) = pk;
        *(uint2*)(lds + LDS_A0 + (32 + si) * 256 + ((colB + 16) ^ sXor)) = pk;
        pk.x = cvtpk(v3.x, v3.y); pk.y = cvtpk(v3.z, v3.w);
        *(uint2*)(lds + LDS_A0 + si * 256 + ((colA + 24) ^ sXor)) = pk;
        *(uint2*)(lds + LDS_A0 + (32 + si) * 256 + ((colB + 24) ^ sXor)) = pk;

        const int sed = tid >> 2, sqq = tid & 3;   // X: thread == its epilogue thread
        const int nodeX = (sed < 32) ? src[p0 + sed] : tgt[p0 + sed - 32];
        sx = *(const float4*)(xembed + (size_t)nodeX * DX + sqq * 4);
    }

    float bin_r[4];
    #pragma unroll
    for (int n = 0; n < 4; ++n) bin_r[n] = bin[16 * n + lane15];

    const int arow = 16 * wv + lane15;
    const int axor = SWZ(arow);

    // issue hidden-layer-0 weight loads NOW (latency hides under L0)
    bf16x8 wcur[8], wnxt[8];
    {
        const unsigned short* whg = wsw + WS_WH / 2;
        #pragma unroll
        for (int j = 0; j < 8; ++j)
            wcur[j] = *(const bf16x8*)(whg + (j * 64 + lane) * 8);
    }

    __syncthreads();   // staging visible

    // ==== layer 0: A0[64x128] @ W0[128x64] -> H0 (no barrier after; see notes) ====
    {
        bf16x8 a[4];
        #pragma unroll
        for (int kk = 0; kk < 4; ++kk)
            a[kk] = *(const bf16x8*)(lds + LDS_A0 + arow * 256 + ((kk * 64 + hi * 16) ^ axor));
        const unsigned short* w0g = wsw + WS_W0 / 2;
        #pragma unroll
        for (int n = 0; n < 4; ++n) {
            f32x4 acc = {0.0f, 0.0f, 0.0f, 0.0f};
            #pragma unroll
            for (int kk = 0; kk < 4; ++kk) {
                const bf16x8 b = *(const bf16x8*)(w0g + ((n * 4 + kk) * 64 + lane) * 8);
                acc = MFMA16(a[kk], b, acc);
            }
            #pragma unroll
            for (int r = 0; r < 4; ++r) {
                const int row = 16 * wv + 4 * hi + r;
                *(__hip_bfloat16*)(lds + LDS_H0 + row * 128 +
                    (((16 * n + lane15) * 2) ^ SWZ(row))) =
                    __float2bfloat16(fmaxf(acc[r] + bin_r[n], 0.0f));
            }
        }
    }
    // No barrier: H0 L0-write -> hidden-read is same-wave in-order; A0 reads are
    // ordered before MA writes by the post-hidden barrier below.

    // ==== 6 hidden layers, H0/H1 ping-pong; weights + bias 1-layer-ahead in regs ====
    float bcur[4], bnxt[4];
    {
        const float* bl = bh + lane15;
        bcur[0] = bl[0]; bcur[1] = bl[16]; bcur[2] = bl[32]; bcur[3] = bl[48];
    }
    #pragma unroll
    for (int l = 0; l < N_HIDDEN; ++l) {
        if (l + 1 < N_HIDDEN) {
            const unsigned short* whg = wsw + WS_WH / 2 + (l + 1) * 4096;
            #pragma unroll
            for (int j = 0; j < 8; ++j)
                wnxt[j] = *(const bf16x8*)(whg + (j * 64 + lane) * 8);
            const float* bl = bh + (l + 1) * 64 + lane15;
            bnxt[0] = bl[0]; bnxt[1] = bl[16]; bnxt[2] = bl[32]; bnxt[3] = bl[48];
        }
        const int sB = (l & 1) ? LDS_H1 : LDS_H0;
        const int dB = (l & 1) ? LDS_H0 : LDS_H1;
        const bf16x8 a0 = *(const bf16x8*)(lds + sB + arow * 128 + ((hi * 16) ^ axor));
        const bf16x8 a1 = *(const bf16x8*)(lds + sB + arow * 128 + ((64 + hi * 16) ^ axor));
        #pragma unroll
        for (int n = 0; n < 4; ++n) {
            f32x4 acc = {0.0f, 0.0f, 0.0f, 0.0f};
            acc = MFMA16(a0, wcur[2 * n + 0], acc);
            acc = MFMA16(a1, wcur[2 * n + 1], acc);
            #pragma unroll
            for (int r = 0; r < 4; ++r) {
                const int row = 16 * wv + 4 * hi + r;
                *(__hip_bfloat16*)(lds + dB + row * 128 +
                    (((16 * n + lane15) * 2) ^ SWZ(row))) =
                    __float2bfloat16(fmaxf(acc[r] + bcur[n], 0.0f));
            }
        }
        #pragma unroll
        for (int j = 0; j < 8; ++j) wcur[j] = wnxt[j];
        bcur[0] = bnxt[0]; bcur[1] = bnxt[1]; bcur[2] = bnxt[2]; bcur[3] = bnxt[3];
    }
    __syncthreads();   // H1 reads done -> MT region writable; A0 reads done -> MA writable

    // ==== final layer: H0 @ Wout -> MA (A0 region) / MT; 4-deep b prefetch ====
    {
        float bo[16];
        #pragma unroll
        for (int n = 0; n < 16; ++n) bo[n] = bout[16 * n + lane15];

        const bf16x8 fa0 = *(const bf16x8*)(lds + LDS_H0 + arow * 128 + ((hi * 16) ^ axor));
        const bf16x8 fa1 = *(const bf16x8*)(lds + LDS_H0 + arow * 128 + ((64 + hi * 16) ^ axor));
        const unsigned short* wog = wsw + WS_WOUT / 2;

        bf16x8 pbA[4], pbB[4];
        #pragma unroll
        for (int n = 0; n < 4; ++n) {
            pbA[n] = *(const bf16x8*)(wog + ((n * 2 + 0) * 64 + lane) * 8);
            pbB[n] = *(const bf16x8*)(wog + ((n * 2 + 1) * 64 + lane) * 8);
        }

        if (wv < 2) {
            // a-edges: MA row-major, conflict-free scalar writes under SWZ
            #pragma unroll
            for (int n = 0; n < 16; ++n) {
                const bf16x8 b0 = pbA[n & 3], b1 = pbB[n & 3];
                if (n + 4 < 16) {
                    pbA[n & 3] = *(const bf16x8*)(wog + (((n + 4) * 2 + 0) * 64 + lane) * 8);
                    pbB[n & 3] = *(const bf16x8*)(wog + (((n + 4) * 2 + 1) * 64 + lane) * 8);
                }
                f32x4 acc = {0.0f, 0.0f, 0.0f, 0.0f};
                acc = MFMA16(fa0, b0, acc);
                acc = MFMA16(fa1, b1, acc);
                #pragma unroll
                for (int r = 0; r < 4; ++r) {
                    const int i = 16 * wv + 4 * hi + r;
                    *(__hip_bfloat16*)(lds + LDS_A0 + i * 512 +
                        (((n * 16 + lane15) * 2) ^ SWZ(i))) =
                        __float2bfloat16(acc[r] + bo[n]);
                }
            }
        } else {
            // b-edges: MT col-major; buffer 16 values per r, write 2x b128 per r
            unsigned int pk0[8], pk1[8], pk2[8], pk3[8];
            float tmp0 = 0.f, tmp1 = 0.f, tmp2 = 0.f, tmp3 = 0.f;
            #pragma unroll
            for (int n = 0; n < 16; ++n) {
                const bf16x8 b0 = pbA[n & 3], b1 = pbB[n & 3];
                if (n + 4 < 16) {
                    pbA[n & 3] = *(const bf16x8*)(wog + (((n + 4) * 2 + 0) * 64 + lane) * 8);
                    pbB[n & 3] = *(const bf16x8*)(wog + (((n + 4) * 2 + 1) * 64 + lane) * 8);
                }
                f32x4 acc = {0.0f, 0.0f, 0.0f, 0.0f};
                acc = MFMA16(fa0, b0, acc);
                acc = MFMA16(fa1, b1, acc);
                const float v0 = acc[0] + bo[n], v1 = acc[1] + bo[n];
                const float v2 = acc[2] + bo[n], v3 = acc[3] + bo[n];
                if (n & 1) {
                    pk0[n >> 1] = cvtpk(tmp0, v0); pk1[n >> 1] = cvtpk(tmp1, v1);
                    pk2[n >> 1] = cvtpk(tmp2, v2); pk3[n >> 1] = cvtpk(tmp3, v3);
                } else {
                    tmp0 = v0; tmp1 = v1; tmp2 = v2; tmp3 = v3;
                }
            }
            const int csp = CSP(lane15);
            #pragma unroll
            for (int r = 0; r < 4; ++r) {
                const int i = 16 * (wv - 2) + 4 * hi + r;
                const int sw = SWZ(i) ^ csp;
                char* base = lds + LDS_MT + i * 512;
                const unsigned int* pkr = (r == 0) ? pk0 : (r == 1) ? pk1 : (r == 2) ? pk2 : pk3;
                *(uint4*)(base + ((lane15 * 32 + 0) ^ sw)) =
                    make_uint4(pkr[0], pkr[1], pkr[2], pkr[3]);
                *(uint4*)(base + ((lane15 * 32 + 16) ^ sw)) =
                    make_uint4(pkr[4], pkr[5], pkr[6], pkr[7]);
            }
        }
    }
    __syncthreads();   // M visible block-wide

    // ==== epilogue: messages + scatter (4 threads/edge); X assembled via shfl ====
    {
        const int e = tid >> 2, q = tid & 3;
        const int i = e & 31;
        const bool isB = (e >= 32);
        float xv[16];
        #pragma unroll
        for (int qq = 0; qq < 4; ++qq) {
            xv[4 * qq + 0] = __shfl(sx.x, qq, 4);
            xv[4 * qq + 1] = __shfl(sx.y, qq, 4);
            xv[4 * qq + 2] = __shfl(sx.z, qq, 4);
            xv[4 * qq + 3] = __shfl(sx.w, qq, 4);
        }
        const int p = p0 + i;
        const float w_e  = isB ? edge_w[p + E_HALF] : edge_w[p];
        const int target = isB ? src[p] : tgt[p];
        const int ixor = SWZ(i);
        if (!isB) {
            #pragma unroll
            for (int jj = 0; jj < 4; ++jj) {
                const int row = 4 * q + jj;
                const uint4 m0 = *(const uint4*)(lds + LDS_A0 + i * 512 + ((row * 32) ^ ixor));
                const uint4 m1 = *(const uint4*)(lds + LDS_A0 + i * 512 + ((row * 32 + 16) ^ ixor));
                float m = bflo(m0.x) * xv[0];
                m = fmaf(bfhi(m0.x), xv[1], m);  m = fmaf(bflo(m0.y), xv[2], m);
                m = fmaf(bfhi(m0.y), xv[3], m);  m = fmaf(bflo(m0.z), xv[4], m);
                m = fmaf(bfhi(m0.z), xv[5], m);  m = fmaf(bflo(m0.w), xv[6], m);
                m = fmaf(bfhi(m0.w), xv[7], m);  m = fmaf(bflo(m1.x), xv[8], m);
                m = fmaf(bfhi(m1.x), xv[9], m);  m = fmaf(bflo(m1.y), xv[10], m);
                m = fmaf(bfhi(m1.y), xv[11], m); m = fmaf(bflo(m1.z), xv[12], m);
                m = fmaf(bfhi(m1.z), xv[13], m); m = fmaf(bflo(m1.w), xv[14], m);
                m = fmaf(bfhi(m1.w), xv[15], m);
                atomicAdd(&newx[(size_t)target * DX + row], w_e * m);
            }
        } else {
            float macc[4] = {0.f, 0.f, 0.f, 0.f};
            #pragma unroll
            for (int c = 0; c < 16; ++c) {
                const uint2 v = *(const uint2*)(lds + LDS_MT + i * 512 +
                                                ((c * 32 + q * 8) ^ ixor ^ CSP(c)));
                const float xc = xv[c];
                macc[0] = fmaf(bflo(v.x), xc, macc[0]);
                macc[1] = fmaf(bfhi(v.x), xc, macc[1]);
                macc[2] = fmaf(bflo(v.y), xc, macc[2]);
                macc[3] = fmaf(bfhi(v.y), xc, macc[3]);
            }
            #pragma unroll
            for (int jj = 0; jj < 4; ++jj)
                atomicAdd(&newx[(size_t)target * DX + 4 * q + jj], w_e * macc[jj]);
        }
        if (q == 0) atomicAdd(&deg[target], w_e);
    }

    // ==== epilogue: orth (one mfma per pair; K=16 of 32 used) ====
    float wsum = 0.0f;
    {
        const bf16x8 zf = {0, 0, 0, 0, 0, 0, 0, 0};
        #pragma unroll
        for (int pp = 0; pp < 8; ++pp) {
            const int pi = 8 * wv + pp;
            const int pxor = SWZ(pi);
            const int offA = (lane15 * 32 + (hi & 1) * 16) ^ pxor;
            const int offB = (lane15 * 32 + (hi & 1) * 16) ^ pxor ^ CSP(lane15);
            bf16x8 af  = *(const bf16x8*)(lds + LDS_A0 + pi * 512 + offA);
            bf16x8 bfr = *(const bf16x8*)(lds + LDS_MT + pi * 512 + offB);
            if (hi >= 2) { af = zf; bfr = zf; }
            f32x4 pr = {0.f, 0.f, 0.f, 0.f};
            pr = MFMA16(af, bfr, pr);
            float ss = 0.0f;
            #pragma unroll
            for (int r = 0; r < 4; ++r) {
                const float d = pr[r] - ((4 * hi + r == lane15) ? 1.0f : 0.0f);
                ss = fmaf(d, d, ss);
            }
            #pragma unroll
            for (int o = 32; o > 0; o >>= 1) ss += __shfl_xor(ss, o, 64);
            wsum += sqrtf(ss);
        }
    }
    // block-reduce orth into 256-slot partial array (scratch in dead MA region)
    __syncthreads();
    if (lane == 0) ((float*)(lds + LDS_A0))[wv] = wsum;
    __syncthreads();
    if (tid == 0) {
        const float* pw = (const float*)(lds + LDS_A0);
        atomicAdd(&orth_part[blockIdx.x & 255], pw[0] + pw[1] + pw[2] + pw[3]);
    }
}

// ---------------- block reduction helper (256-thread blocks) ----------------
__device__ __forceinline__ float block_reduce_256(float v) {
    __shared__ float part[4];
    #pragma unroll
    for (int off = 32; off > 0; off >>= 1) v += __shfl_xor(v, off, 64);
    const int lane = threadIdx.x & 63, wid = threadIdx.x >> 6;
    if (lane == 0) part[wid] = v;
    __syncthreads();
    float s = 0.0f;
    if (threadIdx.x == 0) {
        #pragma unroll
        for (int i = 0; i < 4; ++i) s += part[i];
    }
    return s;
}

// K2: degree-normalize (xmaped in place) + smap MSE
__global__ __launch_bounds__(256) void k_smap(
    const float* __restrict__ xembed, float* __restrict__ nx,
    const float* __restrict__ deg, float* __restrict__ accum)
{
    const int n = blockIdx.x * 256 + threadIdx.x;
    float ss = 0.0f;
    if (n < N_NODES) {
        const float d = deg[n];
        const float inv = 1.0f / fmaxf(d, 1e-20f);
        #pragma unroll
        for (int c = 0; c < DX; ++c) {
            const float v  = nx[(size_t)n * DX + c];
            const float xm = (d > 0.0f) ? v * inv : v;
            nx[(size_t)n * DX + c] = xm;
            const float df = xm - xembed[(size_t)n * DX + c];
            ss = fmaf(df, df, ss);
        }
    }
    ss = block_reduce_256(ss);
    if (threadIdx.x == 0) atomicAdd(&accum[1], ss);
}

// K3: KL on labeled nodes
__global__ __launch_bounds__(256) void k_lbpr(
    const float* __restrict__ ylprob, const float* __restrict__ xmaped,
    const float* __restrict__ clW, const float* __restrict__ clb,
    const int* __restrict__ idvert, float* __restrict__ accum)
{
    const int v = blockIdx.x * 256 + threadIdx.x;
    float kl = 0.0f;
    if (v < N_LABELED) {
        const int n = idvert[v];
        float z[NLAB];
        #pragma unroll
        for (int c = 0; c < NLAB; ++c) z[c] = clb[c];
        #pragma unroll
        for (int i = 0; i < DX; ++i) {
            const float xi = xmaped[(size_t)n * DX + i];
            #pragma unroll
            for (int c = 0; c < NLAB; ++c) z[c] = fmaf(xi, clW[i * NLAB + c], z[c]);
        }
        float mx = z[0];
        #pragma unroll
        for (int c = 1; c < NLAB; ++c) mx = fmaxf(mx, z[c]);
        float se = 0.0f;
        #pragma unroll
        for (int c = 0; c < NLAB; ++c) se += expf(z[c] - mx);
        const float lse = mx + logf(se);
        #pragma unroll
        for (int c = 0; c < NLAB; ++c) {
            const float yl = ylprob[(size_t)n * NLAB + c];
            kl += expf(yl) * (yl - (z[c] - lse));
        }
    }
    kl = block_reduce_256(kl);
    if (threadIdx.x == 0) atomicAdd(&accum[2], kl);
}

// K4: finalize the 4 outputs (f32); sums orth partials
__global__ __launch_bounds__(256) void k_final(
    const float* __restrict__ accum, const float* __restrict__ orth_part,
    float* __restrict__ out)
{
    float v = orth_part[threadIdx.x];
    v = block_reduce_256(v);
    if (threadIdx.x == 0) {
        out[0] = v * (1.0f / (float)E_HALF);
        out[1] = 0.0f;                                // loss_cons == 0 exactly
        out[2] = accum[1] * (1.0f / (float)N_NODES);  // mean*DX/(N*DX) = sum/N
        out[3] = accum[2] * (1.0f / (float)N_LABELED);
    }
}

extern "C" void kernel_launch(void* const* d_in, const int* in_sizes, int n_in,
                              void* d_out, int out_size, void* d_ws, size_t ws_size,
                              hipStream_t stream) {
    const float* xembed = (const float*)d_in[0];
    const float* sembed = (const float*)d_in[1];
    const float* ylprob = (const float*)d_in[2];
    const float* edge_w = (const float*)d_in[3];
    const float* Win    = (const float*)d_in[4];
    const float* bin    = (const float*)d_in[5];
    const float* Wh     = (const float*)d_in[6];
    const float* bh     = (const float*)d_in[7];
    const float* Wout   = (const float*)d_in[8];
    const float* bout   = (const float*)d_in[9];
    const float* clW    = (const float*)d_in[10];
    const float* clb    = (const float*)d_in[11];
    const int*   src    = (const int*)d_in[12];
    const int*   tgt    = (const int*)d_in[13];
    const int*   idvert = (const int*)d_in[16];
    // rev1/rev2 implied: pairs are (p, p+E_HALF)

    unsigned short* wsw = (unsigned short*)d_ws;
    float* wsF       = (float*)((char*)d_ws + WS_FLOATS);
    float* newx      = wsF;
    float* deg       = wsF + (size_t)N_NODES * DX;
    float* accum     = deg + N_NODES;
    float* orth_part = accum + 4;
    const int nzero = N_NODES * DX + N_NODES + 4 + 256;

    k_prep<<<192, 256, 0, stream>>>(Win, Wh, Wout, wsw);
    k_zero<<<512, 256, 0, stream>>>(wsF, nzero);

    k_main<<<NT, 256, LDS_TOTAL, stream>>>(
        xembed, sembed, edge_w, bin, bh, bout, src, tgt, wsw, newx, deg, orth_part);

    k_smap<<<(N_NODES + 255) / 256, 256, 0, stream>>>(xembed, newx, deg, accum);
    k_lbpr<<<(N_LABELED + 255) / 256, 256, 0, stream>>>(ylprob, newx, clW, clb, idvert, accum);
    k_final<<<1, 256, 0, stream>>>(accum, orth_part, (float*)d_out);
}